// Round 1
// baseline (4550.200 us; speedup 1.0000x reference)
//
#include <hip/hip_runtime.h>
#include <hip/hip_fp16.h>
#include <stdint.h>

// ---------------------------------------------------------------------------
// Problem geometry (all compile-time):
//   x: (64, 48, 512, 2, 2) fp32. seq[s,n,f] = x[n, f>>2, 8*s, (f>>1)&1, f&1]
//   (only batch rows n<64 of the 512 are ever used downstream).
//   Layer1 BiGRU: in=192, H=256, 64 steps. Layer2 BiGRU: in=512, H=256.
//   Only final hiddens of layer2 used. dec_h = w_adj @ [hf,hb] + b_adj.
//   Decoder GRU (in=56, H=256) 6 steps, out = w_fc1@h + b_fc1 -> (64,6,56).
// ---------------------------------------------------------------------------

#define HD 256
#define G3 768           // 3*HD
#define NSEQ 64          // batch rows used
#define NSTEP 64         // scan length
#define MROWS 4096       // NSEQ*NSTEP

__device__ __forceinline__ float sigmf(float x) {
    return 1.0f / (1.0f + __expf(-x));
}

// ---------------- weight prep ----------------
// pack WhhT (768x256 row-major) -> [k2][j] u32 of (f16(w[j][2k2]), f16(w[j][2k2+1]))
__global__ __launch_bounds__(256) void pack_whhT(
    const float* __restrict__ w0, const float* __restrict__ w1,
    const float* __restrict__ w2, const float* __restrict__ w3,
    const float* __restrict__ w4,
    uint32_t* __restrict__ o0, uint32_t* __restrict__ o1,
    uint32_t* __restrict__ o2, uint32_t* __restrict__ o3,
    uint32_t* __restrict__ o4)
{
    const float* w; uint32_t* o;
    switch (blockIdx.y) {
        case 0: w = w0; o = o0; break;
        case 1: w = w1; o = o1; break;
        case 2: w = w2; o = o2; break;
        case 3: w = w3; o = o3; break;
        default: w = w4; o = o4; break;
    }
    int idx = blockIdx.x * 256 + threadIdx.x;    // 98304 total
    int k2 = idx / G3, j = idx % G3;
    float a = w[j * HD + 2 * k2];
    float b = w[j * HD + 2 * k2 + 1];
    uint32_t lo = __half_as_ushort(__float2half_rn(a));
    uint32_t hi = __half_as_ushort(__float2half_rn(b));
    o[idx] = lo | (hi << 16);
}

// fp32 transposes for decoder-input / adj / fc1 paths
__global__ __launch_bounds__(256) void prep_small(
    const float* __restrict__ wihd,   // (768,56)
    const float* __restrict__ wadj,   // (256,512)
    const float* __restrict__ wfc1,   // (56,256)
    float* __restrict__ wihdT,        // [v][j] 56x768
    float* __restrict__ wadjT,        // [f][i] 512x256
    float* __restrict__ wfc1T)        // [k][v] 256x56
{
    int idx = blockIdx.x * 256 + threadIdx.x;    // 188416 total
    if (idx < 43008) {
        int v = idx / G3, j = idx % G3;
        wihdT[idx] = wihd[j * 56 + v];
    } else if (idx < 43008 + 131072) {
        int i2 = idx - 43008;
        int f = i2 / HD, i = i2 % HD;
        wadjT[i2] = wadj[i * 512 + f];
    } else {
        int i3 = idx - 174080;
        int k = i3 / 56, v = i3 % 56;
        wfc1T[i3] = wfc1[v * HD + k];
    }
}

// gather seq rows: seqg[(n*64+s)*192 + f] = x[n, f>>2, 8s, (f>>1)&1, f&1]
__global__ __launch_bounds__(256) void gather_seq(
    const float* __restrict__ x, float* __restrict__ seqg)
{
    int idx = blockIdx.x * 256 + threadIdx.x;    // 786432 total
    int f = idx % 192;
    int m = idx / 192;
    int n = m >> 6, s = m & 63;
    seqg[idx] = x[n * 98304 + (f >> 2) * 2048 + s * 32 + (f & 3)];
}

// ---------------- fp32 tiled GEMM with bias: C[m][j] = sum_k A[m][k]*B[j][k] + bias[j]
// M=4096, N=768 fixed; K parameter. grid=(64, 12, 2) where z selects dir.
__global__ __launch_bounds__(256) void gemm_bias(
    const float* __restrict__ A,
    const float* __restrict__ B0, const float* __restrict__ B1,
    const float* __restrict__ bias0, const float* __restrict__ bias1,
    float* __restrict__ C0, float* __restrict__ C1, int K)
{
    const float* B    = blockIdx.z ? B1 : B0;
    const float* bias = blockIdx.z ? bias1 : bias0;
    float*       C    = blockIdx.z ? C1 : C0;
    const int m0 = blockIdx.x * 64;
    const int n0 = blockIdx.y * 64;
    const int tid = threadIdx.x;
    const int tx = tid & 15, ty = tid >> 4;

    __shared__ float As[16][64];
    __shared__ float Bs[16][64];

    const int lm = tid >> 2;         // 0..63
    const int lk = (tid & 3) * 4;    // 0,4,8,12

    float acc[4][4] = {};
    for (int k0 = 0; k0 < K; k0 += 16) {
        float4 a = *(const float4*)(A + (size_t)(m0 + lm) * K + k0 + lk);
        float4 b = *(const float4*)(B + (size_t)(n0 + lm) * K + k0 + lk);
        __syncthreads();
        As[lk + 0][lm] = a.x; As[lk + 1][lm] = a.y;
        As[lk + 2][lm] = a.z; As[lk + 3][lm] = a.w;
        Bs[lk + 0][lm] = b.x; Bs[lk + 1][lm] = b.y;
        Bs[lk + 2][lm] = b.z; Bs[lk + 3][lm] = b.w;
        __syncthreads();
#pragma unroll
        for (int kk = 0; kk < 16; ++kk) {
            const float4 a4 = *(const float4*)&As[kk][ty * 4];
            const float4 b4 = *(const float4*)&Bs[kk][tx * 4];
            const float av[4] = {a4.x, a4.y, a4.z, a4.w};
            const float bv[4] = {b4.x, b4.y, b4.z, b4.w};
#pragma unroll
            for (int i = 0; i < 4; ++i)
#pragma unroll
                for (int j = 0; j < 4; ++j)
                    acc[i][j] += av[i] * bv[j];
        }
    }
#pragma unroll
    for (int i = 0; i < 4; ++i) {
#pragma unroll
        for (int j = 0; j < 4; ++j) {
            C[(size_t)(m0 + ty * 4 + i) * G3 + n0 + tx * 4 + j] =
                acc[i][j] + bias[n0 + tx * 4 + j];
        }
    }
}

// ---------------- register-resident GRU scan ----------------
// 768 threads. Thread j owns Whh row j (128 packed f16x2 = 128 VGPRs).
// h broadcast from LDS as f16 pairs; fp32 accumulate; h itself stays fp32.
// grid = 128 blocks: dir = blockIdx.x&1, n = blockIdx.x>>1.
// mode 0: write per-step h to y1[(n*64+s)*512 + dir*256 + t]
// mode 1: write final h to hfin[(dir*64+n)*256 + t]
__device__ __forceinline__ float dot2f(uint32_t w, uint32_t h, float acc) {
    const __half2 wv = *reinterpret_cast<const __half2*>(&w);
    const __half2 hv = *reinterpret_cast<const __half2*>(&h);
    acc += __half2float(wv.x) * __half2float(hv.x);
    acc += __half2float(wv.y) * __half2float(hv.y);
    return acc;
}

__global__ __launch_bounds__(768, 3) void gru_scan(
    const float* __restrict__ giF, const float* __restrict__ giB,
    const uint32_t* __restrict__ wTF, const uint32_t* __restrict__ wTB,
    const float* __restrict__ bhhF, const float* __restrict__ bhhB,
    float* __restrict__ y1, float* __restrict__ hfin, int mode)
{
    const int dir = blockIdx.x & 1;
    const int n   = blockIdx.x >> 1;
    const int t   = threadIdx.x;
    const float*    gi  = dir ? giB : giF;
    const uint32_t* wT  = dir ? wTB : wTF;
    const float*    bhh = dir ? bhhB : bhhF;

    __shared__ __align__(16) __half h1[HD];
    __shared__ float gh[G3];

    uint32_t w[128];
#pragma unroll
    for (int k2 = 0; k2 < 128; ++k2) w[k2] = wT[k2 * G3 + t];
    const float bh = bhh[t];

    float h_own = 0.0f;
    if (t < HD) h1[t] = __float2half(0.0f);
    __syncthreads();

    for (int step = 0; step < NSTEP; ++step) {
        const int s = dir ? (NSTEP - 1 - step) : step;
        const float* gr = gi + (size_t)(n * NSTEP + s) * G3;
        float acc = bh;
#pragma unroll
        for (int k8 = 0; k8 < 32; ++k8) {
            const uint4 hp = *(const uint4*)(h1 + k8 * 8);
            acc = dot2f(w[4 * k8 + 0], hp.x, acc);
            acc = dot2f(w[4 * k8 + 1], hp.y, acc);
            acc = dot2f(w[4 * k8 + 2], hp.z, acc);
            acc = dot2f(w[4 * k8 + 3], hp.w, acc);
        }
        gh[t] = acc;
        __syncthreads();
        if (t < HD) {
            const float ir = gr[t], iz = gr[HD + t], inn = gr[2 * HD + t];
            const float r  = sigmf(ir + gh[t]);
            const float z  = sigmf(iz + gh[HD + t]);
            const float nn = tanhf(inn + r * gh[2 * HD + t]);
            const float hnew = (1.0f - z) * nn + z * h_own;
            h_own = hnew;
            h1[t] = __float2half(hnew);
            if (mode == 0)
                y1[(size_t)(n * NSTEP + s) * 512 + dir * HD + t] = hnew;
        }
        __syncthreads();
    }
    if (mode == 1 && t < HD)
        hfin[(size_t)(dir * NSEQ + n) * HD + t] = h_own;
}

// ---------------- dec_h = w_adj @ [hf,hb] + b_adj ----------------
__global__ __launch_bounds__(256) void adj_kernel(
    const float* __restrict__ hfin, const float* __restrict__ wadjT,
    const float* __restrict__ badj, float* __restrict__ dech)
{
    const int n = blockIdx.x, t = threadIdx.x;
    __shared__ float comb[512];
    comb[t]      = hfin[(size_t)n * HD + t];
    comb[HD + t] = hfin[(size_t)(NSEQ + n) * HD + t];
    __syncthreads();
    float acc = badj[t];
    for (int f = 0; f < 512; ++f) acc += wadjT[f * HD + t] * comb[f];
    dech[n * HD + t] = acc;
}

// ---------------- decoder: 6 GRU steps + fc1, feeds output back ----------------
__global__ __launch_bounds__(768, 3) void decoder_kernel(
    const float* __restrict__ dech, const uint32_t* __restrict__ wTd,
    const float* __restrict__ wihdT, const float* __restrict__ bihd,
    const float* __restrict__ bhhd, const float* __restrict__ wfc1T,
    const float* __restrict__ bfc1, float* __restrict__ out)
{
    const int n = blockIdx.x, t = threadIdx.x;
    __shared__ __align__(16) __half h1[HD];
    __shared__ float hfp[HD];
    __shared__ float ghs[G3], gis[G3];
    __shared__ float inp[56];

    uint32_t w[128];
#pragma unroll
    for (int k2 = 0; k2 < 128; ++k2) w[k2] = wTd[k2 * G3 + t];
    const float bi = bihd[t], bh = bhhd[t];

    float h_own = 0.0f;
    if (t < HD) {
        const float hv = dech[n * HD + t];
        h_own = hv;
        h1[t] = __float2half(hv);
        hfp[t] = hv;
    }
    if (t < 56) inp[t] = 0.0f;
    __syncthreads();

    for (int step = 0; step < 6; ++step) {
        float acch = bh;
#pragma unroll
        for (int k8 = 0; k8 < 32; ++k8) {
            const uint4 hp = *(const uint4*)(h1 + k8 * 8);
            acch = dot2f(w[4 * k8 + 0], hp.x, acch);
            acch = dot2f(w[4 * k8 + 1], hp.y, acch);
            acch = dot2f(w[4 * k8 + 2], hp.z, acch);
            acch = dot2f(w[4 * k8 + 3], hp.w, acch);
        }
        float acci = bi;
        for (int v = 0; v < 56; ++v) acci += wihdT[v * G3 + t] * inp[v];
        ghs[t] = acch;
        gis[t] = acci;
        __syncthreads();
        if (t < HD) {
            const float r  = sigmf(gis[t] + ghs[t]);
            const float z  = sigmf(gis[HD + t] + ghs[HD + t]);
            const float nn = tanhf(gis[2 * HD + t] + r * ghs[2 * HD + t]);
            const float hnew = (1.0f - z) * nn + z * h_own;
            h_own = hnew;
            h1[t] = __float2half(hnew);
            hfp[t] = hnew;
        }
        __syncthreads();
        if (t < 56) {
            float o = bfc1[t];
            for (int k = 0; k < HD; ++k) o += wfc1T[k * 56 + t] * hfp[k];
            out[n * 336 + step * 56 + t] = o;
            inp[t] = o;
        }
        __syncthreads();
    }
}

// ---------------------------------------------------------------------------
extern "C" void kernel_launch(void* const* d_in, const int* in_sizes, int n_in,
                              void* d_out, int out_size, void* d_ws, size_t ws_size,
                              hipStream_t stream)
{
    const float* x      = (const float*)d_in[0];
    const float* wih1f  = (const float*)d_in[1];
    const float* whh1f  = (const float*)d_in[2];
    const float* bih1f  = (const float*)d_in[3];
    const float* bhh1f  = (const float*)d_in[4];
    const float* wih1b  = (const float*)d_in[5];
    const float* whh1b  = (const float*)d_in[6];
    const float* bih1b  = (const float*)d_in[7];
    const float* bhh1b  = (const float*)d_in[8];
    const float* wih2f  = (const float*)d_in[9];
    const float* whh2f  = (const float*)d_in[10];
    const float* bih2f  = (const float*)d_in[11];
    const float* bhh2f  = (const float*)d_in[12];
    const float* wih2b  = (const float*)d_in[13];
    const float* whh2b  = (const float*)d_in[14];
    const float* bih2b  = (const float*)d_in[15];
    const float* bhh2b  = (const float*)d_in[16];
    const float* wihd   = (const float*)d_in[17];
    const float* whhd   = (const float*)d_in[18];
    const float* bihd   = (const float*)d_in[19];
    const float* bhhd   = (const float*)d_in[20];
    const float* wfc1   = (const float*)d_in[21];
    const float* bfc1   = (const float*)d_in[22];
    const float* wadj   = (const float*)d_in[23];
    const float* badj   = (const float*)d_in[24];

    float* ws = (float*)d_ws;
    // workspace offsets (floats); all multiples of 4 -> 16B aligned
    float* seqg  = ws + 0;              // 786432
    float* gi1f  = ws + 786432;         // 3145728  (also gi2f, after scan1)
    float* gi1b  = ws + 3932160;        // 3145728  (also gi2b)
    float* y1    = ws + 7077888;        // 2097152
    float* hfin  = ws + 9175040;        // 32768
    float* dech  = ws + 9207808;        // 16384
    uint32_t* wt1f  = (uint32_t*)(ws + 9224192);   // 98304 each
    uint32_t* wt1b  = (uint32_t*)(ws + 9322496);
    uint32_t* wt2f  = (uint32_t*)(ws + 9420800);
    uint32_t* wt2b  = (uint32_t*)(ws + 9519104);
    uint32_t* wtd   = (uint32_t*)(ws + 9617408);
    float* wihdT = ws + 9715712;        // 43008
    float* wadjT = ws + 9758720;        // 131072
    float* wfc1T = ws + 9889792;        // 14336
    // total 9904128 floats = 39.6 MB

    pack_whhT<<<dim3(384, 5), 256, 0, stream>>>(
        whh1f, whh1b, whh2f, whh2b, whhd, wt1f, wt1b, wt2f, wt2b, wtd);
    prep_small<<<736, 256, 0, stream>>>(wihd, wadj, wfc1, wihdT, wadjT, wfc1T);
    gather_seq<<<3072, 256, 0, stream>>>(x, seqg);

    // layer 1
    gemm_bias<<<dim3(64, 12, 2), 256, 0, stream>>>(
        seqg, wih1f, wih1b, bih1f, bih1b, gi1f, gi1b, 192);
    gru_scan<<<128, 768, 0, stream>>>(
        gi1f, gi1b, wt1f, wt1b, bhh1f, bhh1b, y1, hfin, 0);

    // layer 2 (gi buffers reused; stream order serializes)
    gemm_bias<<<dim3(64, 12, 2), 256, 0, stream>>>(
        y1, wih2f, wih2b, bih2f, bih2b, gi1f, gi1b, 512);
    gru_scan<<<128, 768, 0, stream>>>(
        gi1f, gi1b, wt2f, wt2b, bhh2f, bhh2b, y1, hfin, 1);

    // decoder head
    adj_kernel<<<64, 256, 0, stream>>>(hfin, wadjT, badj, dech);
    decoder_kernel<<<64, 768, 0, stream>>>(
        dech, wtd, wihdT, bihd, bhhd, wfc1T, bfc1, (float*)d_out);
}

// Round 2
// 558.788 us; speedup vs baseline: 8.1430x; 8.1430x over previous
//
#include <hip/hip_runtime.h>
#include <hip/hip_fp16.h>
#include <stdint.h>

// ---------------------------------------------------------------------------
// Problem geometry (all compile-time):
//   x: (64, 48, 512, 2, 2) fp32. seq[s,n,f] = x[n, f>>2, 8*s, (f>>1)&1, f&1]
//   (only batch rows n<64 of the 512 matter downstream).
//   Layer1 BiGRU: in=192, H=256, 64 steps. Layer2 BiGRU: in=512, H=256.
//   Only final hiddens of layer2 used. dec_h = w_adj @ [hf,hb] + b_adj.
//   Decoder GRU (in=56, H=256) 6 steps, out = w_fc1@h + b_fc1 -> (64,6,56).
// ---------------------------------------------------------------------------

#define HD 256
#define G3 768           // 3*HD
#define NSEQ 64
#define NSTEP 64

typedef _Float16 hvec2 __attribute__((ext_vector_type(2)));

__device__ __forceinline__ float sigmf(float x) {
    return 1.0f / (1.0f + __expf(-x));
}

#if __has_builtin(__builtin_amdgcn_fdot2)
__device__ __forceinline__ float fdot2u(uint32_t w, uint32_t h, float acc) {
    return __builtin_amdgcn_fdot2(__builtin_bit_cast(hvec2, w),
                                  __builtin_bit_cast(hvec2, h), acc, false);
}
#else
__device__ __forceinline__ float fdot2u(uint32_t w, uint32_t h, float acc) {
    const __half2 wv = __builtin_bit_cast(__half2, w);
    const __half2 hv = __builtin_bit_cast(__half2, h);
    acc += __half2float(wv.x) * __half2float(hv.x);
    acc += __half2float(wv.y) * __half2float(hv.y);
    return acc;
}
#endif

__device__ __forceinline__ uint32_t pkh(float a, float b) {
    uint32_t lo = __half_as_ushort(__float2half_rn(a));
    uint32_t hi = __half_as_ushort(__float2half_rn(b));
    return lo | (hi << 16);
}

// 32 named uint4 weight registers (128 VGPRs), statically indexed everywhere.
#define LW_ALL \
  LW(0) LW(1) LW(2) LW(3) LW(4) LW(5) LW(6) LW(7) \
  LW(8) LW(9) LW(10) LW(11) LW(12) LW(13) LW(14) LW(15) \
  LW(16) LW(17) LW(18) LW(19) LW(20) LW(21) LW(22) LW(23) \
  LW(24) LW(25) LW(26) LW(27) LW(28) LW(29) LW(30) LW(31)
#define DOT_ALL \
  DOT(0) DOT(1) DOT(2) DOT(3) DOT(4) DOT(5) DOT(6) DOT(7) \
  DOT(8) DOT(9) DOT(10) DOT(11) DOT(12) DOT(13) DOT(14) DOT(15) \
  DOT(16) DOT(17) DOT(18) DOT(19) DOT(20) DOT(21) DOT(22) DOT(23) \
  DOT(24) DOT(25) DOT(26) DOT(27) DOT(28) DOT(29) DOT(30) DOT(31)

// ---------------- weight prep ----------------
// Repack Whh (768x256 fp32) into f16x2, uint4-granular, thread-coalesced:
//   out_u4[q*768 + j] (q=0..31) holds k = 8q..8q+7 of row j,
//   component r = (w[j][8q+2r], w[j][8q+2r+1]) packed f16x2.
__global__ __launch_bounds__(256) void pack_whhT(
    const float* __restrict__ w0, const float* __restrict__ w1,
    const float* __restrict__ w2, const float* __restrict__ w3,
    const float* __restrict__ w4,
    uint32_t* __restrict__ o0, uint32_t* __restrict__ o1,
    uint32_t* __restrict__ o2, uint32_t* __restrict__ o3,
    uint32_t* __restrict__ o4)
{
    const float* w; uint32_t* o;
    switch (blockIdx.y) {
        case 0: w = w0; o = o0; break;
        case 1: w = w1; o = o1; break;
        case 2: w = w2; o = o2; break;
        case 3: w = w3; o = o3; break;
        default: w = w4; o = o4; break;
    }
    int idx = blockIdx.x * 256 + threadIdx.x;    // 24576 total
    int j = idx >> 5, q = idx & 31;
    const float4 fa = *(const float4*)(w + j * HD + 8 * q);
    const float4 fb = *(const float4*)(w + j * HD + 8 * q + 4);
    uint4 r;
    r.x = pkh(fa.x, fa.y);
    r.y = pkh(fa.z, fa.w);
    r.z = pkh(fb.x, fb.y);
    r.w = pkh(fb.z, fb.w);
    ((uint4*)o)[q * G3 + j] = r;
}

// fp32 transposes for decoder-input / adj / fc1 paths
__global__ __launch_bounds__(256) void prep_small(
    const float* __restrict__ wihd,   // (768,56)
    const float* __restrict__ wadj,   // (256,512)
    const float* __restrict__ wfc1,   // (56,256)
    float* __restrict__ wihdT,        // [v][j] 56x768
    float* __restrict__ wadjT,        // [f][i] 512x256
    float* __restrict__ wfc1T)        // [k][v] 256x56
{
    int idx = blockIdx.x * 256 + threadIdx.x;    // 188416 total
    if (idx < 43008) {
        int v = idx / G3, j = idx % G3;
        wihdT[idx] = wihd[j * 56 + v];
    } else if (idx < 43008 + 131072) {
        int i2 = idx - 43008;
        int f = i2 / HD, i = i2 % HD;
        wadjT[i2] = wadj[i * 512 + f];
    } else {
        int i3 = idx - 174080;
        int k = i3 / 56, v = i3 % 56;
        wfc1T[i3] = wfc1[v * HD + k];
    }
}

// gather seq rows: seqg[(n*64+s)*192 + f] = x[n, f>>2, 8s, (f>>1)&1, f&1]
__global__ __launch_bounds__(256) void gather_seq(
    const float* __restrict__ x, float* __restrict__ seqg)
{
    int idx = blockIdx.x * 256 + threadIdx.x;    // 786432 total
    int f = idx % 192;
    int m = idx / 192;
    int n = m >> 6, s = m & 63;
    seqg[idx] = x[n * 98304 + (f >> 2) * 2048 + s * 32 + (f & 3)];
}

// ---------------- fp32 tiled GEMM with bias: C[m][j] = sum_k A[m][k]*B[j][k] + bias[j]
// M=4096, N=768 fixed; K parameter. grid=(64, 12, 2) where z selects dir.
// LDS tiles XOR-swizzled: element (row k, col m) stored at col ^ ((k>>2)<<4).
__global__ __launch_bounds__(256) void gemm_bias(
    const float* __restrict__ A,
    const float* __restrict__ B0, const float* __restrict__ B1,
    const float* __restrict__ bias0, const float* __restrict__ bias1,
    float* __restrict__ C0, float* __restrict__ C1, int K)
{
    const float* B    = blockIdx.z ? B1 : B0;
    const float* bias = blockIdx.z ? bias1 : bias0;
    float*       C    = blockIdx.z ? C1 : C0;
    const int m0 = blockIdx.x * 64;
    const int n0 = blockIdx.y * 64;
    const int tid = threadIdx.x;
    const int tx = tid & 15, ty = tid >> 4;

    __shared__ float As[16][64];
    __shared__ float Bs[16][64];

    const int lm = tid >> 2;          // 0..63
    const int lk = (tid & 3) * 4;     // 0,4,8,12
    const int sw = lk << 2;           // ((lk>>2)&3)<<4 : 0,16,32,48

    float acc[4][4] = {};
    for (int k0 = 0; k0 < K; k0 += 16) {
        float4 a = *(const float4*)(A + (size_t)(m0 + lm) * K + k0 + lk);
        float4 b = *(const float4*)(B + (size_t)(n0 + lm) * K + k0 + lk);
        __syncthreads();
        As[lk + 0][lm ^ sw] = a.x; As[lk + 1][lm ^ sw] = a.y;
        As[lk + 2][lm ^ sw] = a.z; As[lk + 3][lm ^ sw] = a.w;
        Bs[lk + 0][lm ^ sw] = b.x; Bs[lk + 1][lm ^ sw] = b.y;
        Bs[lk + 2][lm ^ sw] = b.z; Bs[lk + 3][lm ^ sw] = b.w;
        __syncthreads();
#pragma unroll
        for (int kk = 0; kk < 16; ++kk) {
            const int swk = ((kk >> 2) & 3) << 4;
            const float4 a4 = *(const float4*)&As[kk][(ty * 4) ^ swk];
            const float4 b4 = *(const float4*)&Bs[kk][(tx * 4) ^ swk];
            const float av[4] = {a4.x, a4.y, a4.z, a4.w};
            const float bv[4] = {b4.x, b4.y, b4.z, b4.w};
#pragma unroll
            for (int i = 0; i < 4; ++i)
#pragma unroll
                for (int j = 0; j < 4; ++j)
                    acc[i][j] += av[i] * bv[j];
        }
    }
#pragma unroll
    for (int i = 0; i < 4; ++i) {
#pragma unroll
        for (int j = 0; j < 4; ++j) {
            C[(size_t)(m0 + ty * 4 + i) * G3 + n0 + tx * 4 + j] =
                acc[i][j] + bias[n0 + tx * 4 + j];
        }
    }
}

// ---------------- register-resident GRU scan ----------------
// 768 threads, thread j owns Whh row j in 32 named uint4 (128 VGPRs, f16x2).
// h kept in LDS as f16 pairs; v_dot2_f32_f16 accumulate in fp32.
// grid = 128 blocks: dir = blockIdx.x&1, n = blockIdx.x>>1.
__global__ __launch_bounds__(768, 3) void gru_scan(
    const float* __restrict__ giF, const float* __restrict__ giB,
    const uint32_t* __restrict__ wTF, const uint32_t* __restrict__ wTB,
    const float* __restrict__ bhhF, const float* __restrict__ bhhB,
    float* __restrict__ y1, float* __restrict__ hfin, int mode)
{
    const int dir = blockIdx.x & 1;
    const int n   = blockIdx.x >> 1;
    const int t   = threadIdx.x;
    const float* gi = dir ? giB : giF;
    const uint4* wq = (const uint4*)(dir ? wTB : wTF);
    const float  bh = (dir ? bhhB : bhhF)[t];

    __shared__ __align__(16) uint32_t h1u[HD / 2];   // h as 128 f16x2
    __shared__ float s_rz[2 * HD];                   // ir+ghr, iz+ghz
    __shared__ float s_ghn[HD];
    __shared__ float s_inn[HD];

#define LW(i) const uint4 w##i = wq[(i) * G3 + t];
    LW_ALL
#undef LW

    float h_own = 0.0f;
    if (t < HD / 2) h1u[t] = 0u;
    __syncthreads();

    for (int step = 0; step < NSTEP; ++step) {
        const int s = dir ? (NSTEP - 1 - step) : step;
        const float gval = gi[(size_t)(n * NSTEP + s) * G3 + t];  // overlaps matvec
        float a0 = 0.f, a1 = 0.f, a2 = 0.f, a3 = 0.f;
#define DOT(i) { const uint4 hp = *(const uint4*)&h1u[4 * (i)]; \
        a0 = fdot2u(w##i.x, hp.x, a0); a1 = fdot2u(w##i.y, hp.y, a1); \
        a2 = fdot2u(w##i.z, hp.z, a2); a3 = fdot2u(w##i.w, hp.w, a3); }
        DOT_ALL
#undef DOT
        const float acc = bh + ((a0 + a1) + (a2 + a3));
        if (t < 2 * HD) {
            s_rz[t] = gval + acc;
        } else {
            s_ghn[t - 2 * HD] = acc;
            s_inn[t - 2 * HD] = gval;
        }
        __syncthreads();
        if (t < HD) {
            const float r  = sigmf(s_rz[t]);
            const float z  = sigmf(s_rz[HD + t]);
            const float nn = tanhf(s_inn[t] + r * s_ghn[t]);
            const float hnew = (1.0f - z) * nn + z * h_own;
            h_own = hnew;
            ((__half*)h1u)[t] = __float2half(hnew);
            if (mode == 0)
                y1[(size_t)(n * NSTEP + s) * 512 + dir * HD + t] = hnew;
        }
        __syncthreads();
    }
    if (mode == 1 && t < HD)
        hfin[(size_t)(dir * NSEQ + n) * HD + t] = h_own;
}

// ---------------- dec_h = w_adj @ [hf,hb] + b_adj ----------------
__global__ __launch_bounds__(256) void adj_kernel(
    const float* __restrict__ hfin, const float* __restrict__ wadjT,
    const float* __restrict__ badj, float* __restrict__ dech)
{
    const int n = blockIdx.x, t = threadIdx.x;
    __shared__ float comb[512];
    comb[t]      = hfin[(size_t)n * HD + t];
    comb[HD + t] = hfin[(size_t)(NSEQ + n) * HD + t];
    __syncthreads();
    float acc = badj[t];
    for (int f = 0; f < 512; ++f) acc += wadjT[f * HD + t] * comb[f];
    dech[n * HD + t] = acc;
}

// ---------------- decoder: 6 GRU steps + fc1, feeds output back ----------------
__global__ __launch_bounds__(768, 3) void decoder_kernel(
    const float* __restrict__ dech, const uint32_t* __restrict__ wTd,
    const float* __restrict__ wihdT, const float* __restrict__ bihd,
    const float* __restrict__ bhhd, const float* __restrict__ wfc1T,
    const float* __restrict__ bfc1, float* __restrict__ out)
{
    const int n = blockIdx.x, t = threadIdx.x;
    __shared__ __align__(16) uint32_t h1u[HD / 2];
    __shared__ float hfp[HD];
    __shared__ float s_rz[2 * HD];
    __shared__ float s_ghn[HD];
    __shared__ float s_inn[HD];
    __shared__ float inp[56];

    const uint4* wq = (const uint4*)wTd;
#define LW(i) const uint4 w##i = wq[(i) * G3 + t];
    LW_ALL
#undef LW
    const float bi = bihd[t], bh = bhhd[t];

    float h_own = 0.0f;
    if (t < HD) {
        const float hv = dech[n * HD + t];
        h_own = hv;
        ((__half*)h1u)[t] = __float2half(hv);
        hfp[t] = hv;
    }
    if (t < 56) inp[t] = 0.0f;
    __syncthreads();

    for (int step = 0; step < 6; ++step) {
        float acci = bi;
#pragma unroll
        for (int v = 0; v < 56; ++v) acci += wihdT[v * G3 + t] * inp[v];
        float a0 = 0.f, a1 = 0.f, a2 = 0.f, a3 = 0.f;
#define DOT(i) { const uint4 hp = *(const uint4*)&h1u[4 * (i)]; \
        a0 = fdot2u(w##i.x, hp.x, a0); a1 = fdot2u(w##i.y, hp.y, a1); \
        a2 = fdot2u(w##i.z, hp.z, a2); a3 = fdot2u(w##i.w, hp.w, a3); }
        DOT_ALL
#undef DOT
        const float acch = bh + ((a0 + a1) + (a2 + a3));
        if (t < 2 * HD) {
            s_rz[t] = acci + acch;
        } else {
            s_ghn[t - 2 * HD] = acch;
            s_inn[t - 2 * HD] = acci;
        }
        __syncthreads();
        if (t < HD) {
            const float r  = sigmf(s_rz[t]);
            const float z  = sigmf(s_rz[HD + t]);
            const float nn = tanhf(s_inn[t] + r * s_ghn[t]);
            const float hnew = (1.0f - z) * nn + z * h_own;
            h_own = hnew;
            ((__half*)h1u)[t] = __float2half(hnew);
            hfp[t] = hnew;
        }
        __syncthreads();
        if (t < 56) {
            float o = bfc1[t];
            for (int k = 0; k < HD; ++k) o += wfc1T[k * 56 + t] * hfp[k];
            out[n * 336 + step * 56 + t] = o;
            inp[t] = o;
        }
        __syncthreads();
    }
}

// ---------------------------------------------------------------------------
extern "C" void kernel_launch(void* const* d_in, const int* in_sizes, int n_in,
                              void* d_out, int out_size, void* d_ws, size_t ws_size,
                              hipStream_t stream)
{
    const float* x      = (const float*)d_in[0];
    const float* wih1f  = (const float*)d_in[1];
    const float* whh1f  = (const float*)d_in[2];
    const float* bih1f  = (const float*)d_in[3];
    const float* bhh1f  = (const float*)d_in[4];
    const float* wih1b  = (const float*)d_in[5];
    const float* whh1b  = (const float*)d_in[6];
    const float* bih1b  = (const float*)d_in[7];
    const float* bhh1b  = (const float*)d_in[8];
    const float* wih2f  = (const float*)d_in[9];
    const float* whh2f  = (const float*)d_in[10];
    const float* bih2f  = (const float*)d_in[11];
    const float* bhh2f  = (const float*)d_in[12];
    const float* wih2b  = (const float*)d_in[13];
    const float* whh2b  = (const float*)d_in[14];
    const float* bih2b  = (const float*)d_in[15];
    const float* bhh2b  = (const float*)d_in[16];
    const float* wihd   = (const float*)d_in[17];
    const float* whhd   = (const float*)d_in[18];
    const float* bihd   = (const float*)d_in[19];
    const float* bhhd   = (const float*)d_in[20];
    const float* wfc1   = (const float*)d_in[21];
    const float* bfc1   = (const float*)d_in[22];
    const float* wadj   = (const float*)d_in[23];
    const float* badj   = (const float*)d_in[24];

    float* ws = (float*)d_ws;
    float* seqg  = ws + 0;              // 786432
    float* gi1f  = ws + 786432;         // 3145728  (also gi2f, after scan1)
    float* gi1b  = ws + 3932160;        // 3145728  (also gi2b)
    float* y1    = ws + 7077888;        // 2097152
    float* hfin  = ws + 9175040;        // 32768
    float* dech  = ws + 9207808;        // 16384
    uint32_t* wt1f  = (uint32_t*)(ws + 9224192);   // 98304 each
    uint32_t* wt1b  = (uint32_t*)(ws + 9322496);
    uint32_t* wt2f  = (uint32_t*)(ws + 9420800);
    uint32_t* wt2b  = (uint32_t*)(ws + 9519104);
    uint32_t* wtd   = (uint32_t*)(ws + 9617408);
    float* wihdT = ws + 9715712;        // 43008
    float* wadjT = ws + 9758720;        // 131072
    float* wfc1T = ws + 9889792;        // 14336

    pack_whhT<<<dim3(96, 5), 256, 0, stream>>>(
        whh1f, whh1b, whh2f, whh2b, whhd, wt1f, wt1b, wt2f, wt2b, wtd);
    prep_small<<<736, 256, 0, stream>>>(wihd, wadj, wfc1, wihdT, wadjT, wfc1T);
    gather_seq<<<3072, 256, 0, stream>>>(x, seqg);

    // layer 1
    gemm_bias<<<dim3(64, 12, 2), 256, 0, stream>>>(
        seqg, wih1f, wih1b, bih1f, bih1b, gi1f, gi1b, 192);
    gru_scan<<<128, 768, 0, stream>>>(
        gi1f, gi1b, wt1f, wt1b, bhh1f, bhh1b, y1, hfin, 0);

    // layer 2 (gi buffers reused; stream order serializes)
    gemm_bias<<<dim3(64, 12, 2), 256, 0, stream>>>(
        y1, wih2f, wih2b, bih2f, bih2b, gi1f, gi1b, 512);
    gru_scan<<<128, 768, 0, stream>>>(
        gi1f, gi1b, wt2f, wt2b, bhh2f, bhh2b, y1, hfin, 1);

    // decoder head
    adj_kernel<<<64, 256, 0, stream>>>(hfin, wadjT, badj, dech);
    decoder_kernel<<<64, 768, 0, stream>>>(
        dech, wtd, wihdT, bihd, bhhd, wfc1T, bfc1, (float*)d_out);
}